// Round 1
// baseline (69.815 us; speedup 1.0000x reference)
//
#include <hip/hip_runtime.h>

#define B_ 32
#define T_ 512
#define D_ 256
#define P_ 8
#define BT (B_*T_)
#define ROWS 32
#define KT 32
#define NKT (D_/KT)

typedef float f4 __attribute__((ext_vector_type(4)));

// ---------------- kernel 0: W1 [e][d] -> w1t [d][e] ----------------
__global__ void k_transpose(const float* __restrict__ W1, float* __restrict__ w1t) {
  int d = blockIdx.x;        // 256
  int e = threadIdx.x;       // 256
  w1t[d * D_ + e] = W1[e * D_ + d];
}

// ---------------- kernel 1: fused GEMM1 + GEMM2 + argmax -> dur ----------------
// 512 blocks x 256 threads. Block handles 32 rows of flattened (B*T, D) x.
// Wave w owns rows w*8..w*8+7; lane owns e = lane*4..lane*4+3.
__global__ __launch_bounds__(256, 2) void k_dur(
    const float* __restrict__ x, const float* __restrict__ w1t,
    const float* __restrict__ b1, const float* __restrict__ W2,
    const float* __restrict__ b2, int* __restrict__ dur)
{
  __shared__ float xs[ROWS][D_];   // 32 KB, x tile (row-major, rows contiguous)
  __shared__ float wst[KT][D_];    // 32 KB, W1^T k-tile: wst[dd][e]

  const int tid  = threadIdx.x;
  const int lane = tid & 63;
  const int wave = tid >> 6;
  const int row0 = blockIdx.x * ROWS;

  // stage x tile: one global_load_lds (16B/lane = 1KB = one row) per row
  for (int i = 0; i < 8; ++i) {
    int r = wave * 8 + i;
    const float* g = x + (size_t)(row0 + r) * D_ + lane * 4;
    __builtin_amdgcn_global_load_lds(
        (const __attribute__((address_space(1))) void*)g,
        (__attribute__((address_space(3))) void*)&xs[r][0], 16, 0, 0);
  }

  f4 b1v = *(const f4*)(b1 + lane * 4);
  f4 acc[8];
  #pragma unroll
  for (int i = 0; i < 8; ++i) acc[i] = b1v;

  for (int kt = 0; kt < NKT; ++kt) {
    // stage W1^T k-tile rows (8 per wave)
    for (int i = 0; i < 8; ++i) {
      int dd = wave * 8 + i;
      const float* g = w1t + (size_t)(kt * KT + dd) * D_ + lane * 4;
      __builtin_amdgcn_global_load_lds(
          (const __attribute__((address_space(1))) void*)g,
          (__attribute__((address_space(3))) void*)&wst[dd][0], 16, 0, 0);
    }
    __syncthreads();

    f4 loc[8];   // per-k-tile partial accumulators (shorter FMA chains -> less fp error)
    #pragma unroll
    for (int i = 0; i < 8; ++i) loc[i] = (f4){0.f, 0.f, 0.f, 0.f};

    #pragma unroll
    for (int dq = 0; dq < KT / 4; ++dq) {
      f4 wv[4];
      #pragma unroll
      for (int j = 0; j < 4; ++j) wv[j] = *(const f4*)&wst[dq * 4 + j][lane * 4];
      #pragma unroll
      for (int i = 0; i < 8; ++i) {
        f4 xv = *(const f4*)&xs[wave * 8 + i][kt * KT + dq * 4];  // wave-uniform broadcast
        loc[i] += xv.x * wv[0];
        loc[i] += xv.y * wv[1];
        loc[i] += xv.z * wv[2];
        loc[i] += xv.w * wv[3];
      }
    }
    #pragma unroll
    for (int i = 0; i < 8; ++i) acc[i] += loc[i];
    __syncthreads();
  }

  // relu
  #pragma unroll
  for (int i = 0; i < 8; ++i)
    #pragma unroll
    for (int c = 0; c < 4; ++c) acc[i][c] = fmaxf(acc[i][c], 0.f);

  // GEMM2 partials: lane's 4 e's vs all 8 W2 rows
  f4 w2r[P_];
  #pragma unroll
  for (int p = 0; p < P_; ++p) w2r[p] = *(const f4*)(W2 + p * D_ + lane * 4);
  float b2r[P_];
  #pragma unroll
  for (int p = 0; p < P_; ++p) b2r[p] = b2[p];

  float v[64];
  #pragma unroll
  for (int r = 0; r < 8; ++r)
    #pragma unroll
    for (int p = 0; p < P_; ++p) {
      f4 h = acc[r];
      v[r * 8 + p] = h[0]*w2r[p][0] + h[1]*w2r[p][1] + h[2]*w2r[p][2] + h[3]*w2r[p][3];
    }

  // split-butterfly: xor 1,2,4 halves the value set each step (32+16+8 shfls)
  #pragma unroll
  for (int step = 0; step < 3; ++step) {
    const int s = 1 << step;
    const int half = 32 >> step;
    const bool upper = (lane & s) != 0;
    #pragma unroll
    for (int i = 0; i < half; ++i) {
      float a = v[i], b = v[i + half];
      float send = upper ? a : b;
      float recv = __shfl_xor(send, s, 64);
      v[i] = (upper ? b : a) + recv;
    }
  }
  // accumulate across the 8-lane groups: xor 8,16,32 (24 shfls)
  #pragma unroll
  for (int s = 8; s < 64; s <<= 1)
    #pragma unroll
    for (int i = 0; i < 8; ++i) v[i] += __shfl_xor(v[i], s, 64);

  // lane l (<8) now holds all 8 logits of row rev3(l); first-max argmax
  if (lane < 8) {
    float best = v[0] + b2r[0];
    int am = 0;
    #pragma unroll
    for (int p = 1; p < P_; ++p) {
      float L = v[p] + b2r[p];
      if (L > best) { best = L; am = p; }
    }
    int r = ((lane & 1) << 2) | (lane & 2) | ((lane & 4) >> 2);
    dur[row0 + wave * 8 + r] = am;
  }
}

// ---------------- kernel 2: per-batch inclusive scan + scatter src ----------------
__global__ void k_scan(const int* __restrict__ dur, int* __restrict__ src, int mel) {
  __shared__ int sh[T_];
  int t = threadIdx.x, b = blockIdx.x;
  int d = dur[b * T_ + t];
  sh[t] = d;
  __syncthreads();
  for (int s = 1; s < T_; s <<= 1) {
    int a = (t >= s) ? sh[t - s] : 0;
    __syncthreads();
    sh[t] += a;
    __syncthreads();
  }
  int cs = sh[t];
  int start = cs - d;
  int total = sh[T_ - 1];
  for (int m = start; m < cs; ++m) src[b * mel + m] = t;          // searchsorted(cs, m, 'right') == t
  for (int m = total + t; m < mel; m += T_) src[b * mel + m] = -1; // masked tail
}

// ---------------- kernel 3: gather/expand ----------------
__global__ __launch_bounds__(256) void k_gather(
    const float* __restrict__ x, const int* __restrict__ src,
    float* __restrict__ out, int mel)
{
  int lane = threadIdx.x & 63;
  int wave = threadIdx.x >> 6;
  int m = blockIdx.x * 4 + wave;
  int b = blockIdx.y;
  if (m >= mel) return;
  int s = src[b * mel + m];
  f4 val = {0.f, 0.f, 0.f, 0.f};
  if (s >= 0) val = *(const f4*)(x + ((size_t)b * T_ + s) * D_ + lane * 4);
  *(f4*)(out + ((size_t)b * mel + m) * D_ + lane * 4) = val;
}

extern "C" void kernel_launch(void* const* d_in, const int* in_sizes, int n_in,
                              void* d_out, int out_size, void* d_ws, size_t ws_size,
                              hipStream_t stream) {
  const float* x  = (const float*)d_in[0];
  const float* W1 = (const float*)d_in[1];
  const float* b1 = (const float*)d_in[2];
  const float* W2 = (const float*)d_in[3];
  const float* b2 = (const float*)d_in[4];
  float* out = (float*)d_out;

  int mel = out_size / (B_ * D_);   // 3584 (mel_max_length lives on device; derive from out_size)

  float* w1t = (float*)d_ws;                                  // 256 KB
  int*   dur = (int*)((char*)d_ws + D_ * D_ * sizeof(float)); // 64 KB
  int*   src = dur + BT;                                      // B*mel*4 = 448 KB

  k_transpose<<<D_, D_, 0, stream>>>(W1, w1t);
  k_dur<<<BT / ROWS, 256, 0, stream>>>(x, w1t, b1, W2, b2, dur);
  k_scan<<<B_, T_, 0, stream>>>(dur, src, mel);
  k_gather<<<dim3((mel + 3) / 4, B_), 256, 0, stream>>>(x, src, out, mel);
}